// Round 3
// baseline (1114.936 us; speedup 1.0000x reference)
//
#include <hip/hip_runtime.h>
#include <cstdint>
#include <cstddef>

// VectorQuantizer: x (16,128,4096) f32, W (1024,128) f32
// out = [quantized_st 8388608 | indices 65536 (as float) | loss 1]
//
// R3: bit-exact numpy-f32 replication (unchanged math), W delivered via
// uniform-address GLOBAL loads into lane-replicated VGPRs (no LDS in the
// main loop -> removes the 34 GB LDS-BW bottleneck measured in R2).
//  - 64B chunks (4 x float4), 4 rotating reg buffers, prefetch distance 3
//  - 2 interleaved code chains (A/B) per group; each chain strictly
//    d-ascending sequential FMA (matches OpenBLAS sgemm -> absmax 0)
//  - h=0 scans codes ascending (strict <), h=1 descending (<=): both give
//    numpy first-occurrence argmin, and prefetch overrun stays in-bounds.

#define BB 16
#define DD 128
#define TT 4096
#define KK 1024
#define NROW 65536
#define QSIZE 8388608
#define IDX_BASE QSIZE
#define LOSS_IDX (QSIZE + NROW)
#define COMMIT 0.25f
#define TPB 256
#define RPB 128           // rows per block (2 threads per row)

// optimization barrier: keep value as-is, block fp contraction across it
__device__ __forceinline__ float fb(float v) {
    asm volatile("" : "+v"(v));
    return v;
}

// Kernel 1: b_k = numpy-pairwise sum of fl(W[k][d]^2); zero the loss slot.
__global__ void vq_prep(const float* __restrict__ W, float* __restrict__ wsq,
                        float* __restrict__ d_out) {
    int k = blockIdx.x * blockDim.x + threadIdx.x;
    if (k == 0 && blockIdx.x == 0) d_out[LOSS_IDX] = 0.f;
    if (k < KK) {
        const float* Wr = W + (size_t)k * DD;
        float rr[8];
        #pragma unroll
        for (int j = 0; j < 8; ++j) {
            float w = Wr[j];
            float pp = w * w;
            pp = fb(pp);
            rr[j] = pp;
        }
        #pragma unroll
        for (int i = 8; i <= 120; i += 8) {
            #pragma unroll
            for (int j = 0; j < 8; ++j) {
                float w = Wr[i + j];
                float pp = w * w;
                pp = fb(pp);
                rr[j] += pp;
            }
        }
        wsq[k] = ((rr[0] + rr[1]) + (rr[2] + rr[3])) + ((rr[4] + rr[5]) + (rr[6] + rr[7]));
    }
}

// chunk j (j=0..15) within a 1KB 2-code group block:
//   j even -> code LO (first 512B), k = j/2, byte off = k*64
//   j odd  -> code HI (second 512B), k = j/2, byte off = 512 + k*64
#define OFFB(j) (((j) & 1) * 512 + ((j) >> 1) * 64)

template <int H>
__device__ __forceinline__ void scan_half(const char* __restrict__ wp0,
                                          const float* __restrict__ bbuf,
                                          const float (&xr)[DD], float a,
                                          float& best, int& bk) {
    constexpr int STEPB = (H == 0) ? 1024 : -1024;
    const char* wp = wp0;

    float4 wb[4][4];   // [slot][4 float4] = one 64B chunk per slot

    // prologue: chunks 0,1,2 of group 0 into slots 0,1,2
    #pragma unroll
    for (int j = 0; j < 3; ++j) {
        const float4* pp = (const float4*)(wp + OFFB(j));
        wb[j][0] = pp[0]; wb[j][1] = pp[1]; wb[j][2] = pp[2]; wb[j][3] = pp[3];
    }

    #pragma unroll 1
    for (int g = 0; g < 512; g += 2) {    // 256 groups of 2 codes
        // ||w||^2 for this group's two codes (LDS broadcast, hoisted early)
        float bbA, bbB;
        if (H == 0) { bbA = bbuf[g];             bbB = bbuf[g + 1]; }
        else        { int p = 1022 - g;  bbA = bbuf[p]; bbB = bbuf[p + 1]; }

        float acA = 0.f, acB = 0.f;
        #pragma unroll
        for (int j = 0; j < 16; ++j) {
            // prefetch chunk j+3 (possibly first chunks of the next group)
            const int pj = j + 3;
            const int poff = (pj < 16) ? OFFB(pj) : (STEPB + OFFB(pj - 16));
            const int sp = pj & 3;
            {
                const float4* pp = (const float4*)(wp + poff);
                wb[sp][0] = pp[0]; wb[sp][1] = pp[1];
                wb[sp][2] = pp[2]; wb[sp][3] = pp[3];
            }
            // consume chunk j: 16 seq-FMAs on chain A (j even) / B (j odd)
            const int sc = j & 3;
            const int k  = j >> 1;
            float ac = (j & 1) ? acB : acA;
            #pragma unroll
            for (int q = 0; q < 4; ++q) {
                float4 w4 = wb[sc][q];
                ac = __builtin_fmaf(xr[k * 16 + q * 4 + 0], w4.x, ac);
                ac = __builtin_fmaf(xr[k * 16 + q * 4 + 1], w4.y, ac);
                ac = __builtin_fmaf(xr[k * 16 + q * 4 + 2], w4.z, ac);
                ac = __builtin_fmaf(xr[k * 16 + q * 4 + 3], w4.w, ac);
            }
            if (j & 1) acB = ac; else acA = ac;
        }

        if (H == 0) {
            const int cA = g, cB = g + 1;      // ascending, strict <
            { float tw = acA + acA; float t1 = a + bbA; float dist = t1 - tw;
              if (dist < best) { best = dist; bk = cA; } }
            { float tw = acB + acB; float t1 = a + bbB; float dist = t1 - tw;
              if (dist < best) { best = dist; bk = cB; } }
        } else {
            const int p = 1022 - g;            // descending, <= (HI then LO)
            { float tw = acB + acB; float t1 = a + bbB; float dist = t1 - tw;
              if (dist <= best) { best = dist; bk = p + 1; } }
            { float tw = acA + acA; float t1 = a + bbA; float dist = t1 - tw;
              if (dist <= best) { best = dist; bk = p; } }
        }

        wp += STEPB;
    }
}

__global__ __launch_bounds__(TPB, 2)
void vq_main(const float* __restrict__ x, const float* __restrict__ W,
             const float* __restrict__ wsq, float* __restrict__ d_out) {
    const int tid   = threadIdx.x;
    const int row_l = tid & (RPB - 1);
    const int h = __builtin_amdgcn_readfirstlane(tid >> 7);   // wave-uniform half id
    const int r = blockIdx.x * RPB + row_l;
    const int b = r >> 12;                 // T = 4096
    const int t = r & (TT - 1);
    const float* xb = x + (size_t)b * DD * TT + t;

    __shared__ float bbuf[KK];             // 4 KB: ||w||^2
    __shared__ float ms[RPB];
    __shared__ int   mk[RPB];
    __shared__ int   fk[RPB];

    // x row -> 128 VGPRs (coalesced: consecutive t across lanes)
    float xr[DD];
    #pragma unroll
    for (int d = 0; d < DD; ++d) xr[d] = xb[(size_t)d * TT];

    // a_r: numpy pairwise of fl(x_d^2)
    float rr[8];
    #pragma unroll
    for (int j = 0; j < 8; ++j) {
        float pp = xr[j] * xr[j];
        pp = fb(pp);
        rr[j] = pp;
    }
    #pragma unroll
    for (int i = 8; i <= 120; i += 8) {
        #pragma unroll
        for (int j = 0; j < 8; ++j) {
            float pp = xr[i + j] * xr[i + j];
            pp = fb(pp);
            rr[j] += pp;
        }
    }
    const float a = ((rr[0] + rr[1]) + (rr[2] + rr[3])) + ((rr[4] + rr[5]) + (rr[6] + rr[7]));

    // stage ||w||^2 into LDS
    #pragma unroll
    for (int s = 0; s < 4; ++s) bbuf[tid + TPB * s] = wsq[tid + TPB * s];
    __syncthreads();

    // taint W base with an opaque zero VGPR -> forces VMEM (not SMEM) loads
    unsigned int vz = 0;
    asm volatile("" : "+v"(vz));
    const char* wbase = (const char*)W + (size_t)vz;

    float best = 3.4e38f;
    int bk = 0;
    if (h == 0) {
        scan_half<0>(wbase, bbuf, xr, a, best, bk);
    } else {
        scan_half<1>(wbase + 511 * 1024, bbuf, xr, a, best, bk);
    }

    // merge halves: h0 covers codes 0..511 and wins ties (first occurrence)
    if (h == 1) { ms[row_l] = best; mk[row_l] = bk; }
    __syncthreads();
    if (h == 0) {
        int kf = (ms[row_l] < best) ? mk[row_l] : bk;
        fk[row_l] = kf;
        d_out[IDX_BASE + r] = (float)kf;
    }
    __syncthreads();
    const int kf = fk[row_l];

    // epilogue: quantized_st = fl(x + fl(q - x)); loss partial
    const float* Wk = W + (size_t)kf * DD;
    float* outq = d_out + (size_t)b * DD * TT + t;
    float acc = 0.f;
    if (h == 0) {
        const float4* Wk4 = (const float4*)Wk;
        #pragma unroll
        for (int dq = 0; dq < 16; ++dq) {
            float4 q4 = Wk4[dq];
            int d0 = dq * 4;
            { float xv = xr[d0 + 0]; float dlt = q4.x - xv; outq[(size_t)(d0 + 0) * TT] = xv + dlt; acc = fmaf(dlt, dlt, acc); }
            { float xv = xr[d0 + 1]; float dlt = q4.y - xv; outq[(size_t)(d0 + 1) * TT] = xv + dlt; acc = fmaf(dlt, dlt, acc); }
            { float xv = xr[d0 + 2]; float dlt = q4.z - xv; outq[(size_t)(d0 + 2) * TT] = xv + dlt; acc = fmaf(dlt, dlt, acc); }
            { float xv = xr[d0 + 3]; float dlt = q4.w - xv; outq[(size_t)(d0 + 3) * TT] = xv + dlt; acc = fmaf(dlt, dlt, acc); }
        }
    } else {
        const float4* Wk4 = (const float4*)Wk + 16;
        #pragma unroll
        for (int dq = 0; dq < 16; ++dq) {
            float4 q4 = Wk4[dq];
            int d0 = 64 + dq * 4;
            { float xv = xr[d0 + 0]; float dlt = q4.x - xv; outq[(size_t)(d0 + 0) * TT] = xv + dlt; acc = fmaf(dlt, dlt, acc); }
            { float xv = xr[d0 + 1]; float dlt = q4.y - xv; outq[(size_t)(d0 + 1) * TT] = xv + dlt; acc = fmaf(dlt, dlt, acc); }
            { float xv = xr[d0 + 2]; float dlt = q4.z - xv; outq[(size_t)(d0 + 2) * TT] = xv + dlt; acc = fmaf(dlt, dlt, acc); }
            { float xv = xr[d0 + 3]; float dlt = q4.w - xv; outq[(size_t)(d0 + 3) * TT] = xv + dlt; acc = fmaf(dlt, dlt, acc); }
        }
    }

    // block-reduce loss partial -> one atomic per block
    #pragma unroll
    for (int off = 32; off > 0; off >>= 1) acc += __shfl_down(acc, off, 64);
    __shared__ float wred[4];
    const int wid = tid >> 6;
    if ((tid & 63) == 0) wred[wid] = acc;
    __syncthreads();
    if (tid == 0) {
        float ssum = (wred[0] + wred[1]) + (wred[2] + wred[3]);
        atomicAdd(&d_out[LOSS_IDX], ssum * (COMMIT / (float)QSIZE));
    }
}

extern "C" void kernel_launch(void* const* d_in, const int* in_sizes, int n_in,
                              void* d_out, int out_size, void* d_ws, size_t ws_size,
                              hipStream_t stream) {
    const float* x = (const float*)d_in[0];
    const float* W = (const float*)d_in[1];
    float* out = (float*)d_out;
    float* wsq = (float*)d_ws;   // 1024 floats of scratch

    vq_prep<<<4, 256, 0, stream>>>(W, wsq, out);
    vq_main<<<NROW / RPB, TPB, 0, stream>>>(x, W, wsq, out);
}

// Round 6
// 594.784 us; speedup vs baseline: 1.8745x; 1.8745x over previous
//
#include <hip/hip_runtime.h>
#include <cstdint>
#include <cstddef>

// VectorQuantizer: x (16,128,4096) f32, W (1024,128) f32
// out = [quantized_st 8388608 | indices 65536 (as float) | loss 1]
//
// R6 (= R4 resubmitted; two infra failures): same bit-exact numpy-f32
// arithmetic as R2 (absmax 0), but W delivered via wave-uniform SCALAR loads
// (s_load -> SGPR, v_fmac_f32 with SGPR src). Scalar pipe is separate from
// LDS (R2 bottleneck) and per-lane VMEM (R3 bottleneck). 4 threads/row
// (256 codes each) -> 4096 waves -> ~3 waves/SIMD hide the s_load waits.

#define BB 16
#define DD 128
#define TT 4096
#define KK 1024
#define NROW 65536
#define QSIZE 8388608
#define IDX_BASE QSIZE
#define LOSS_IDX (QSIZE + NROW)
#define COMMIT 0.25f
#define TPB 256
#define RPB 64            // rows per block (4 threads per row)
#define SEG 4             // segments (waves) per row
#define CPS 256           // codes per segment

// optimization barrier: keep value as-is, block fp contraction across it
__device__ __forceinline__ float fb(float v) {
    asm volatile("" : "+v"(v));
    return v;
}

// Kernel 1: b_k = numpy-pairwise sum of fl(W[k][d]^2); zero the loss slot.
__global__ void vq_prep(const float* __restrict__ W, float* __restrict__ wsq,
                        float* __restrict__ d_out) {
    int k = blockIdx.x * blockDim.x + threadIdx.x;
    if (k == 0 && blockIdx.x == 0) d_out[LOSS_IDX] = 0.f;
    if (k < KK) {
        const float* Wr = W + (size_t)k * DD;
        float rr[8];
        #pragma unroll
        for (int j = 0; j < 8; ++j) {
            float w = Wr[j];
            float pp = w * w;
            pp = fb(pp);
            rr[j] = pp;
        }
        #pragma unroll
        for (int i = 8; i <= 120; i += 8) {
            #pragma unroll
            for (int j = 0; j < 8; ++j) {
                float w = Wr[i + j];
                float pp = w * w;
                pp = fb(pp);
                rr[j] += pp;
            }
        }
        wsq[k] = ((rr[0] + rr[1]) + (rr[2] + rr[3])) + ((rr[4] + rr[5]) + (rr[6] + rr[7]));
    }
}

__global__ __launch_bounds__(TPB, 3)
void vq_main(const float* __restrict__ x, const float* __restrict__ W,
             const float* __restrict__ wsq, float* __restrict__ d_out) {
    const int tid   = threadIdx.x;
    const int row_l = tid & (RPB - 1);                        // = lane
    const int q = __builtin_amdgcn_readfirstlane(tid >> 6);   // wave-uniform segment
    const int r = blockIdx.x * RPB + row_l;
    const int b = r >> 12;                 // T = 4096
    const int t = r & (TT - 1);
    const float* xb = x + (size_t)b * DD * TT + t;

    __shared__ float bbuf[KK];             // 4 KB: ||w||^2
    __shared__ float ms[SEG][RPB];
    __shared__ int   mk[SEG][RPB];
    __shared__ int   fk[RPB];

    // x row -> 128 VGPRs (coalesced: consecutive t across lanes)
    float xr[DD];
    #pragma unroll
    for (int d = 0; d < DD; ++d) xr[d] = xb[(size_t)d * TT];

    // a_r: numpy pairwise of fl(x_d^2)
    float rr[8];
    #pragma unroll
    for (int j = 0; j < 8; ++j) {
        float pp = xr[j] * xr[j];
        pp = fb(pp);
        rr[j] = pp;
    }
    #pragma unroll
    for (int i = 8; i <= 120; i += 8) {
        #pragma unroll
        for (int j = 0; j < 8; ++j) {
            float pp = xr[i + j] * xr[i + j];
            pp = fb(pp);
            rr[j] += pp;
        }
    }
    const float a = ((rr[0] + rr[1]) + (rr[2] + rr[3])) + ((rr[4] + rr[5]) + (rr[6] + rr[7]));

    // stage ||w||^2 into LDS
    #pragma unroll
    for (int s = 0; s < 4; ++s) bbuf[tid + TPB * s] = wsq[tid + TPB * s];
    __syncthreads();

    // scan codes [q*256, (q+1)*256): 2 codes per iter, interleaved seq-FMA
    // chains (each chain strictly d-ascending -> matches BLAS sgemm bits)
    float best = 3.4e38f;
    int bk = 0;
    const int c0 = q * CPS;
    #pragma unroll 1
    for (int g = 0; g < CPS; g += 2) {
        const int c = c0 + g;                                  // uniform
        const float* __restrict__ Wg = W + (size_t)c * DD;     // uniform base
        float acA = 0.f, acB = 0.f;
        #pragma unroll
        for (int d = 0; d < DD; d += 4) {
            float wA0 = Wg[d + 0],      wA1 = Wg[d + 1];
            float wA2 = Wg[d + 2],      wA3 = Wg[d + 3];
            float wB0 = Wg[DD + d + 0], wB1 = Wg[DD + d + 1];
            float wB2 = Wg[DD + d + 2], wB3 = Wg[DD + d + 3];
            acA = __builtin_fmaf(xr[d + 0], wA0, acA);
            acB = __builtin_fmaf(xr[d + 0], wB0, acB);
            acA = __builtin_fmaf(xr[d + 1], wA1, acA);
            acB = __builtin_fmaf(xr[d + 1], wB1, acB);
            acA = __builtin_fmaf(xr[d + 2], wA2, acA);
            acB = __builtin_fmaf(xr[d + 2], wB2, acB);
            acA = __builtin_fmaf(xr[d + 3], wA3, acA);
            acB = __builtin_fmaf(xr[d + 3], wB3, acB);
        }
        // ascending code order, strict < => numpy first-occurrence argmin
        { float tw = acA + acA; float t1 = a + bbuf[c + 0];
          float dist = t1 - tw;
          if (dist < best) { best = dist; bk = c + 0; } }
        { float tw = acB + acB; float t1 = a + bbuf[c + 1];
          float dist = t1 - tw;
          if (dist < best) { best = dist; bk = c + 1; } }
    }

    // merge the 4 segments per row; segment order ascending, strict < keeps
    // first-occurrence tie semantics (segments cover contiguous code ranges)
    ms[q][row_l] = best; mk[q][row_l] = bk;
    __syncthreads();
    if (q == 0) {
        float m = ms[0][row_l]; int kf = mk[0][row_l];
        #pragma unroll
        for (int s = 1; s < SEG; ++s) {
            float v = ms[s][row_l];
            if (v < m) { m = v; kf = mk[s][row_l]; }
        }
        fk[row_l] = kf;
        d_out[IDX_BASE + r] = (float)kf;
    }
    __syncthreads();
    const int kf = fk[row_l];

    // epilogue: quantized_st = fl(x + fl(q - x)); loss partial.
    // segment q handles d in [q*32, q*32+32).
    const float4* Wk4 = (const float4*)(W + (size_t)kf * DD) + q * 8;
    float* outq = d_out + (size_t)b * DD * TT + t;
    float acc = 0.f;
    const int dbase = q * 32;
    #pragma unroll
    for (int dq = 0; dq < 8; ++dq) {
        float4 q4 = Wk4[dq];
        int d0 = dbase + dq * 4;
        { float xv = xr[d0 + 0]; float dlt = q4.x - xv; outq[(size_t)(d0 + 0) * TT] = xv + dlt; acc = fmaf(dlt, dlt, acc); }
        { float xv = xr[d0 + 1]; float dlt = q4.y - xv; outq[(size_t)(d0 + 1) * TT] = xv + dlt; acc = fmaf(dlt, dlt, acc); }
        { float xv = xr[d0 + 2]; float dlt = q4.z - xv; outq[(size_t)(d0 + 2) * TT] = xv + dlt; acc = fmaf(dlt, dlt, acc); }
        { float xv = xr[d0 + 3]; float dlt = q4.w - xv; outq[(size_t)(d0 + 3) * TT] = xv + dlt; acc = fmaf(dlt, dlt, acc); }
    }

    // block-reduce loss partial -> one atomic per block
    #pragma unroll
    for (int off = 32; off > 0; off >>= 1) acc += __shfl_down(acc, off, 64);
    __shared__ float wred[4];
    const int wid = tid >> 6;
    if ((tid & 63) == 0) wred[wid] = acc;
    __syncthreads();
    if (tid == 0) {
        float ssum = (wred[0] + wred[1]) + (wred[2] + wred[3]);
        atomicAdd(&d_out[LOSS_IDX], ssum * (COMMIT / (float)QSIZE));
    }
}

extern "C" void kernel_launch(void* const* d_in, const int* in_sizes, int n_in,
                              void* d_out, int out_size, void* d_ws, size_t ws_size,
                              hipStream_t stream) {
    const float* x = (const float*)d_in[0];
    const float* W = (const float*)d_in[1];
    float* out = (float*)d_out;
    float* wsq = (float*)d_ws;   // 1024 floats of scratch

    vq_prep<<<4, 256, 0, stream>>>(W, wsq, out);
    vq_main<<<NROW / RPB, TPB, 0, stream>>>(x, W, wsq, out);
}

// Round 7
// 529.921 us; speedup vs baseline: 2.1040x; 1.1224x over previous
//
#include <hip/hip_runtime.h>
#include <cstdint>
#include <cstddef>

// VectorQuantizer: x (16,128,4096) f32, W (1024,128) f32
// out = [quantized_st 8388608 | indices 65536 (as float) | loss 1]
//
// R7: R6 structure (W via wave-uniform s_load -> SGPR, 4 segments/row) with
// the scratch-spill bug fixed: R6's epilogue indexed xr[q*32+...] with
// RUNTIME q, demoting xr[128] to scratch (VGPR_Count=84 proved it). Now the
// epilogue dispatches on uniform q into 4 template instantiations with
// compile-time xr indices -> xr stays in VGPRs.
// Bit-exact numpy-f32 arithmetic unchanged from the passing R2/R6.

#define BB 16
#define DD 128
#define TT 4096
#define KK 1024
#define NROW 65536
#define QSIZE 8388608
#define IDX_BASE QSIZE
#define LOSS_IDX (QSIZE + NROW)
#define COMMIT 0.25f
#define TPB 256
#define RPB 64            // rows per block (4 threads per row)
#define SEG 4             // segments (waves) per row
#define CPS 256           // codes per segment

// optimization barrier: keep value as-is, block fp contraction across it
__device__ __forceinline__ float fb(float v) {
    asm volatile("" : "+v"(v));
    return v;
}

// Kernel 1: b_k = numpy-pairwise sum of fl(W[k][d]^2); zero the loss slot.
__global__ void vq_prep(const float* __restrict__ W, float* __restrict__ wsq,
                        float* __restrict__ d_out) {
    int k = blockIdx.x * blockDim.x + threadIdx.x;
    if (k == 0 && blockIdx.x == 0) d_out[LOSS_IDX] = 0.f;
    if (k < KK) {
        const float* Wr = W + (size_t)k * DD;
        float rr[8];
        #pragma unroll
        for (int j = 0; j < 8; ++j) {
            float w = Wr[j];
            float pp = w * w;
            pp = fb(pp);
            rr[j] = pp;
        }
        #pragma unroll
        for (int i = 8; i <= 120; i += 8) {
            #pragma unroll
            for (int j = 0; j < 8; ++j) {
                float w = Wr[i + j];
                float pp = w * w;
                pp = fb(pp);
                rr[j] += pp;
            }
        }
        wsq[k] = ((rr[0] + rr[1]) + (rr[2] + rr[3])) + ((rr[4] + rr[5]) + (rr[6] + rr[7]));
    }
}

// Epilogue for segment base DB (compile-time): quantized_st = fl(x+fl(q-x)),
// accumulate loss partial. All xr indices are compile-time constants.
template <int DB>
__device__ __forceinline__ void epi(const float (&xr)[DD],
                                    const float* __restrict__ Wk,
                                    float* __restrict__ outq, float& acc) {
    const float4* Wk4 = (const float4*)Wk + (DB / 4);
    #pragma unroll
    for (int dq = 0; dq < 8; ++dq) {
        float4 q4 = Wk4[dq];
        { float xv = xr[DB + dq * 4 + 0]; float dlt = q4.x - xv; outq[(size_t)(DB + dq * 4 + 0) * TT] = xv + dlt; acc = fmaf(dlt, dlt, acc); }
        { float xv = xr[DB + dq * 4 + 1]; float dlt = q4.y - xv; outq[(size_t)(DB + dq * 4 + 1) * TT] = xv + dlt; acc = fmaf(dlt, dlt, acc); }
        { float xv = xr[DB + dq * 4 + 2]; float dlt = q4.z - xv; outq[(size_t)(DB + dq * 4 + 2) * TT] = xv + dlt; acc = fmaf(dlt, dlt, acc); }
        { float xv = xr[DB + dq * 4 + 3]; float dlt = q4.w - xv; outq[(size_t)(DB + dq * 4 + 3) * TT] = xv + dlt; acc = fmaf(dlt, dlt, acc); }
    }
}

__global__ __launch_bounds__(TPB, 3)
void vq_main(const float* __restrict__ x, const float* __restrict__ W,
             const float* __restrict__ wsq, float* __restrict__ d_out) {
    const int tid   = threadIdx.x;
    const int row_l = tid & (RPB - 1);                        // = lane
    const int q = __builtin_amdgcn_readfirstlane(tid >> 6);   // wave-uniform segment
    const int r = blockIdx.x * RPB + row_l;
    const int b = r >> 12;                 // T = 4096
    const int t = r & (TT - 1);
    const float* xb = x + (size_t)b * DD * TT + t;

    __shared__ float bbuf[KK];             // 4 KB: ||w||^2
    __shared__ float ms[SEG][RPB];
    __shared__ int   mk[SEG][RPB];
    __shared__ int   fk[RPB];

    // x row -> 128 VGPRs (coalesced: consecutive t across lanes)
    float xr[DD];
    #pragma unroll
    for (int d = 0; d < DD; ++d) xr[d] = xb[(size_t)d * TT];

    // a_r: numpy pairwise of fl(x_d^2)
    float rr[8];
    #pragma unroll
    for (int j = 0; j < 8; ++j) {
        float pp = xr[j] * xr[j];
        pp = fb(pp);
        rr[j] = pp;
    }
    #pragma unroll
    for (int i = 8; i <= 120; i += 8) {
        #pragma unroll
        for (int j = 0; j < 8; ++j) {
            float pp = xr[i + j] * xr[i + j];
            pp = fb(pp);
            rr[j] += pp;
        }
    }
    const float a = ((rr[0] + rr[1]) + (rr[2] + rr[3])) + ((rr[4] + rr[5]) + (rr[6] + rr[7]));

    // stage ||w||^2 into LDS
    #pragma unroll
    for (int s = 0; s < 4; ++s) bbuf[tid + TPB * s] = wsq[tid + TPB * s];
    __syncthreads();

    // scan codes [q*256, (q+1)*256): 2 codes per iter, interleaved seq-FMA
    // chains (each chain strictly d-ascending -> matches BLAS sgemm bits)
    float best = 3.4e38f;
    int bk = 0;
    const int c0 = q * CPS;
    #pragma unroll 1
    for (int g = 0; g < CPS; g += 2) {
        const int c = c0 + g;                                  // uniform
        const float* __restrict__ Wg = W + (size_t)c * DD;     // uniform base
        float acA = 0.f, acB = 0.f;
        #pragma unroll
        for (int d = 0; d < DD; d += 4) {
            float wA0 = Wg[d + 0],      wA1 = Wg[d + 1];
            float wA2 = Wg[d + 2],      wA3 = Wg[d + 3];
            float wB0 = Wg[DD + d + 0], wB1 = Wg[DD + d + 1];
            float wB2 = Wg[DD + d + 2], wB3 = Wg[DD + d + 3];
            acA = __builtin_fmaf(xr[d + 0], wA0, acA);
            acB = __builtin_fmaf(xr[d + 0], wB0, acB);
            acA = __builtin_fmaf(xr[d + 1], wA1, acA);
            acB = __builtin_fmaf(xr[d + 1], wB1, acB);
            acA = __builtin_fmaf(xr[d + 2], wA2, acA);
            acB = __builtin_fmaf(xr[d + 2], wB2, acB);
            acA = __builtin_fmaf(xr[d + 3], wA3, acA);
            acB = __builtin_fmaf(xr[d + 3], wB3, acB);
        }
        // ascending code order, strict < => numpy first-occurrence argmin
        { float tw = acA + acA; float t1 = a + bbuf[c + 0];
          float dist = t1 - tw;
          if (dist < best) { best = dist; bk = c + 0; } }
        { float tw = acB + acB; float t1 = a + bbuf[c + 1];
          float dist = t1 - tw;
          if (dist < best) { best = dist; bk = c + 1; } }
    }

    // merge the 4 segments per row; segment order ascending, strict < keeps
    // first-occurrence tie semantics (segments cover contiguous code ranges)
    ms[q][row_l] = best; mk[q][row_l] = bk;
    __syncthreads();
    if (q == 0) {
        float m = ms[0][row_l]; int kf = mk[0][row_l];
        #pragma unroll
        for (int s = 1; s < SEG; ++s) {
            float v = ms[s][row_l];
            if (v < m) { m = v; kf = mk[s][row_l]; }
        }
        fk[row_l] = kf;
        d_out[IDX_BASE + r] = (float)kf;
    }
    __syncthreads();
    const int kf = fk[row_l];

    // epilogue: segment q handles d in [q*32, q*32+32); compile-time dispatch
    // keeps every xr index constant -> no scratch demotion (R6 bug).
    const float* Wk = W + (size_t)kf * DD;
    float* outq = d_out + (size_t)b * DD * TT + t;
    float acc = 0.f;
    if      (q == 0) epi<0 >(xr, Wk, outq, acc);
    else if (q == 1) epi<32>(xr, Wk, outq, acc);
    else if (q == 2) epi<64>(xr, Wk, outq, acc);
    else             epi<96>(xr, Wk, outq, acc);

    // block-reduce loss partial -> one atomic per block
    #pragma unroll
    for (int off = 32; off > 0; off >>= 1) acc += __shfl_down(acc, off, 64);
    __shared__ float wred[4];
    const int wid = tid >> 6;
    if ((tid & 63) == 0) wred[wid] = acc;
    __syncthreads();
    if (tid == 0) {
        float ssum = (wred[0] + wred[1]) + (wred[2] + wred[3]);
        atomicAdd(&d_out[LOSS_IDX], ssum * (COMMIT / (float)QSIZE));
    }
}

extern "C" void kernel_launch(void* const* d_in, const int* in_sizes, int n_in,
                              void* d_out, int out_size, void* d_ws, size_t ws_size,
                              hipStream_t stream) {
    const float* x = (const float*)d_in[0];
    const float* W = (const float*)d_in[1];
    float* out = (float*)d_out;
    float* wsq = (float*)d_ws;   // 1024 floats of scratch

    vq_prep<<<4, 256, 0, stream>>>(W, wsq, out);
    vq_main<<<NROW / RPB, TPB, 0, stream>>>(x, W, wsq, out);
}